// Round 1
// baseline (83.000 us; speedup 1.0000x reference)
//
#include <hip/hip_runtime.h>
#include <math.h>

namespace {

constexpr int kB = 2;
constexpr int kD = 1024;
constexpr int kL = 1024;
constexpr int kN = 16;
constexpr int kChunks = 16;
constexpr int kClen = kL / kChunks;  // 64

// Pad linear LDS index: chunks are 64 apart (stride 256B = bank-aliased);
// +1 element per chunk staggers banks across concurrently-read chunks.
__device__ __forceinline__ int padi(int l) { return l + (l >> 6); }

__global__ __launch_bounds__(256)
void selscan(const float* __restrict__ u,
             const float* __restrict__ delta,
             const float* __restrict__ A,
             const float* __restrict__ Bm,
             const float* __restrict__ Cm,
             const float* __restrict__ Dv,
             const float* __restrict__ z,
             float* __restrict__ out)
{
    __shared__ float2 sdd[kL + kChunks];   // {dt, dt*u}, padded
    __shared__ float  su[kL];              // u (linear, float4 access only)
    __shared__ float  sy[kL + kChunks];    // y, padded
    __shared__ float  s_a[kChunks][kN];    // chunk decay product
    __shared__ float  s_x[kChunks][kN];    // chunk local-scan final
    __shared__ float  s_ci[kChunks][kN];   // chunk carry-in

    const int bd = blockIdx.x;
    const int b  = bd / kD;
    const int d  = bd % kD;
    const int t  = threadIdx.x;
    const int n  = t & (kN - 1);
    const int chunk = t >> 4;
    const int l0 = chunk * kClen;

    const float* up = u     + (size_t)bd * kL;
    const float* dp = delta + (size_t)bd * kL;
    const float* zp = z     + (size_t)bd * kL;
    float*       op = out   + (size_t)bd * kL;
    const float* Bp = Bm + ((size_t)b * kN + n) * kL;
    const float* Cp = Cm + ((size_t)b * kN + n) * kL;

    const float A_dn = A[d * kN + n];
    const float D_d  = Dv[d];

    // ---- Stage: dt = softplus(delta), dt*u, u (coalesced float4 in) ----
    {
        float4 dv = ((const float4*)dp)[t];
        float4 uv = ((const float4*)up)[t];
        float sp0 = fmaxf(dv.x, 0.f) + log1pf(__expf(-fabsf(dv.x)));
        float sp1 = fmaxf(dv.y, 0.f) + log1pf(__expf(-fabsf(dv.y)));
        float sp2 = fmaxf(dv.z, 0.f) + log1pf(__expf(-fabsf(dv.z)));
        float sp3 = fmaxf(dv.w, 0.f) + log1pf(__expf(-fabsf(dv.w)));
        int l = 4 * t;
        sdd[padi(l + 0)] = make_float2(sp0, sp0 * uv.x);
        sdd[padi(l + 1)] = make_float2(sp1, sp1 * uv.y);
        sdd[padi(l + 2)] = make_float2(sp2, sp2 * uv.z);
        sdd[padi(l + 3)] = make_float2(sp3, sp3 * uv.w);
        ((float4*)su)[t] = uv;
    }
    __syncthreads();

    // ---- Pass A: local scan from 0 over this thread's chunk ----
    float x = 0.f;
    float dtsum = 0.f;
    #pragma unroll 4
    for (int s = 0; s < kClen; s += 4) {
        float4 b4 = *(const float4*)(Bp + l0 + s);
        float bb[4] = {b4.x, b4.y, b4.z, b4.w};
        #pragma unroll
        for (int j = 0; j < 4; ++j) {
            float2 dd = sdd[padi(l0 + s + j)];
            x = __expf(dd.x * A_dn) * x + dd.y * bb[j];
            dtsum += dd.x;
        }
    }
    s_a[chunk][n] = __expf(dtsum * A_dn);  // = prod_s exp(dt_s * A)
    s_x[chunk][n] = x;
    __syncthreads();

    // ---- Carry combine: 16-step sequential scan over chunks, per n ----
    if (t < kN) {
        float carry = 0.f;
        #pragma unroll
        for (int c = 0; c < kChunks; ++c) {
            s_ci[c][t] = carry;
            carry = s_a[c][t] * carry + s_x[c][t];
        }
    }
    __syncthreads();

    // ---- Pass B: recompute local scan with carry-in, reduce y over n ----
    float xb = s_ci[chunk][n];
    #pragma unroll 4
    for (int s = 0; s < kClen; s += 4) {
        float4 b4 = *(const float4*)(Bp + l0 + s);
        float4 c4 = *(const float4*)(Cp + l0 + s);
        float bb[4] = {b4.x, b4.y, b4.z, b4.w};
        float cc[4] = {c4.x, c4.y, c4.z, c4.w};
        #pragma unroll
        for (int j = 0; j < 4; ++j) {
            int l = l0 + s + j;
            float2 dd = sdd[padi(l)];
            xb = __expf(dd.x * A_dn) * xb + dd.y * bb[j];
            float yv = xb * cc[j];
            // sum over the 16 n-lanes (consecutive within the wave)
            yv += __shfl_xor(yv, 1);
            yv += __shfl_xor(yv, 2);
            yv += __shfl_xor(yv, 4);
            yv += __shfl_xor(yv, 8);
            if (n == 0) sy[padi(l)] = yv;
        }
    }
    __syncthreads();

    // ---- Epilogue: out = (y + u*D) * silu(z), coalesced float4 I/O ----
    {
        int l = 4 * t;
        float y0 = sy[padi(l + 0)];
        float y1 = sy[padi(l + 1)];
        float y2 = sy[padi(l + 2)];
        float y3 = sy[padi(l + 3)];
        float4 uv = ((float4*)su)[t];
        float4 zv = ((const float4*)zp)[t];
        float4 o;
        o.x = (y0 + uv.x * D_d) * zv.x / (1.f + __expf(-zv.x));
        o.y = (y1 + uv.y * D_d) * zv.y / (1.f + __expf(-zv.y));
        o.z = (y2 + uv.z * D_d) * zv.z / (1.f + __expf(-zv.z));
        o.w = (y3 + uv.w * D_d) * zv.w / (1.f + __expf(-zv.w));
        ((float4*)op)[t] = o;
    }
}

}  // namespace

extern "C" void kernel_launch(void* const* d_in, const int* in_sizes, int n_in,
                              void* d_out, int out_size, void* d_ws, size_t ws_size,
                              hipStream_t stream) {
    const float* u     = (const float*)d_in[0];
    const float* delta = (const float*)d_in[1];
    const float* A     = (const float*)d_in[2];
    const float* Bm    = (const float*)d_in[3];
    const float* Cm    = (const float*)d_in[4];
    const float* Dv    = (const float*)d_in[5];
    const float* z     = (const float*)d_in[6];
    float* out = (float*)d_out;

    dim3 grid(kB * kD);
    dim3 block(256);
    hipLaunchKernelGGL(selscan, grid, block, 0, stream,
                       u, delta, A, Bm, Cm, Dv, z, out);
}

// Round 2
// 38.621 us; speedup vs baseline: 2.1491x; 2.1491x over previous
//
#include <hip/hip_runtime.h>
#include <math.h>

namespace {

constexpr int kD = 1024;
constexpr int kL = 1024;
constexpr int kN = 16;
constexpr int kE = 8;    // elements (l) per thread
constexpr int kJ = 8;    // n-states per thread
constexpr int kT = 256;  // threads per block; block = one (b,d)

__global__ __launch_bounds__(kT, 2)
void selscan(const float* __restrict__ u,
             const float* __restrict__ delta,
             const float* __restrict__ A,
             const float* __restrict__ Bm,
             const float* __restrict__ Cm,
             const float* __restrict__ Dv,
             const float* __restrict__ z,
             float* __restrict__ out)
{
    // wave carry summaries: [wave][nh][j]
    __shared__ float sw_a[4][2][kJ];
    __shared__ float sw_x[4][2][kJ];

    const int bd   = blockIdx.x;
    const int b    = bd >> 10;          // kD = 1024
    const int d    = bd & (kD - 1);
    const int t    = threadIdx.x;
    const int lane = t & 63;
    const int wave = t >> 6;
    const int chunk = t >> 1;           // 0..127, 8 elements each
    const int nh   = t & 1;             // which half of n
    const int n0   = nh * kJ;
    const int l0   = chunk * kE;

    const float* dp = delta + (size_t)bd * kL + l0;
    const float* up = u     + (size_t)bd * kL + l0;

    // ---- A[d][n0..n0+7] (uniform per (block, nh)) ----
    float Aj[kJ];
    {
        float4 a0 = *(const float4*)(A + d * kN + n0);
        float4 a1 = *(const float4*)(A + d * kN + n0 + 4);
        Aj[0]=a0.x; Aj[1]=a0.y; Aj[2]=a0.z; Aj[3]=a0.w;
        Aj[4]=a1.x; Aj[5]=a1.y; Aj[6]=a1.z; Aj[7]=a1.w;
    }

    // ---- dt = softplus(delta), dtu = dt*u for this chunk ----
    float dt[kE], dtu[kE];
    {
        float4 d0 = *(const float4*)(dp);
        float4 d1 = *(const float4*)(dp + 4);
        float4 u0 = *(const float4*)(up);
        float4 u1 = *(const float4*)(up + 4);
        float dv[kE] = {d0.x,d0.y,d0.z,d0.w,d1.x,d1.y,d1.z,d1.w};
        float uv[kE] = {u0.x,u0.y,u0.z,u0.w,u1.x,u1.y,u1.z,u1.w};
        #pragma unroll
        for (int s = 0; s < kE; ++s) {
            float sp = fmaxf(dv[s], 0.f) + log1pf(__expf(-fabsf(dv[s])));
            dt[s]  = sp;
            dtu[s] = sp * uv[s];
        }
    }

    // ---- Phase 1: local scan per n, caching xl (local state) and P (cumdecay) ----
    float xl[kJ][kE];   // local scan value (zero-init carry)
    float P [kJ][kE];   // cumulative decay prod_{k<=s} exp(dt_k * A_j)
    const int  rowbase = (b << 4) + n0;
    #pragma unroll
    for (int j = 0; j < kJ; ++j) {
        const float* Bp = Bm + ((size_t)(rowbase + j)) * kL + l0;
        float4 b0 = *(const float4*)(Bp);
        float4 b1 = *(const float4*)(Bp + 4);
        float Bv[kE] = {b0.x,b0.y,b0.z,b0.w,b1.x,b1.y,b1.z,b1.w};
        float x = 0.f, p = 1.f;
        float aj = Aj[j];
        #pragma unroll
        for (int s = 0; s < kE; ++s) {
            float e = __expf(dt[s] * aj);
            x = e * x + dtu[s] * Bv[s];
            p = p * e;
            xl[j][s] = x;
            P [j][s] = p;
        }
    }

    // ---- Cross-chunk carry: Hillis-Steele inclusive scan over lanes (stride 2) ----
    // state composition: (A,X) then (B,Y) -> (A*B, B*X + Y)
    float a_s[kJ], x_s[kJ];
    #pragma unroll
    for (int j = 0; j < kJ; ++j) { a_s[j] = P[j][kE-1]; x_s[j] = xl[j][kE-1]; }

    #pragma unroll
    for (int dlt = 2; dlt <= 32; dlt <<= 1) {
        #pragma unroll
        for (int j = 0; j < kJ; ++j) {
            float ain = __shfl_up(a_s[j], dlt, 64);
            float xin = __shfl_up(x_s[j], dlt, 64);
            bool act = (lane >= dlt);
            ain = act ? ain : 1.f;
            xin = act ? xin : 0.f;
            x_s[j] = fmaf(a_s[j], xin, x_s[j]);  // use pre-update a (self)
            a_s[j] = a_s[j] * ain;
        }
    }

    // wave summaries (lanes 62/63 hold the wave-inclusive totals for nh=0/1)
    if (lane >= 62) {
        #pragma unroll
        for (int j = 0; j < kJ; ++j) {
            sw_a[wave][lane & 1][j] = a_s[j];
            sw_x[wave][lane & 1][j] = x_s[j];
        }
    }
    __syncthreads();

    // in-wave exclusive prefix (shift by one chunk = 2 lanes)
    float ea[kJ], ex[kJ];
    #pragma unroll
    for (int j = 0; j < kJ; ++j) {
        float av = __shfl_up(a_s[j], 2, 64);
        float xv = __shfl_up(x_s[j], 2, 64);
        ea[j] = (lane >= 2) ? av : 1.f;
        ex[j] = (lane >= 2) ? xv : 0.f;
    }

    // prefix over preceding waves
    float wx[kJ];
    #pragma unroll
    for (int j = 0; j < kJ; ++j) wx[j] = 0.f;
    #pragma unroll
    for (int w = 0; w < 4; ++w) {
        if (w < wave) {
            #pragma unroll
            for (int j = 0; j < kJ; ++j)
                wx[j] = fmaf(sw_a[w][nh][j], wx[j], sw_x[w][nh][j]);
        }
    }

    // carry into this thread's chunk: apply wave prefix, then in-wave exclusive
    float carry[kJ];
    #pragma unroll
    for (int j = 0; j < kJ; ++j) carry[j] = fmaf(ea[j], wx[j], ex[j]);

    // ---- Phase 2: corrected states * C, accumulate y over this thread's n ----
    float y[kE];
    #pragma unroll
    for (int s = 0; s < kE; ++s) y[s] = 0.f;

    #pragma unroll
    for (int j = 0; j < kJ; ++j) {
        const float* Cp = Cm + ((size_t)(rowbase + j)) * kL + l0;
        float4 c0 = *(const float4*)(Cp);
        float4 c1 = *(const float4*)(Cp + 4);
        float Cv[kE] = {c0.x,c0.y,c0.z,c0.w,c1.x,c1.y,c1.z,c1.w};
        float cj = carry[j];
        #pragma unroll
        for (int s = 0; s < kE; ++s) {
            float xt = fmaf(cj, P[j][s], xl[j][s]);
            y[s] = fmaf(xt, Cv[s], y[s]);
        }
    }

    // combine the two n-halves (lane pairs)
    #pragma unroll
    for (int s = 0; s < kE; ++s) y[s] += __shfl_xor(y[s], 1, 64);

    // ---- Epilogue: each thread of the pair writes 4 of the 8 elements ----
    const float D_d = Dv[d];
    float y0, y1, y2, y3;
    if (nh == 0) { y0 = y[0]; y1 = y[1]; y2 = y[2]; y3 = y[3]; }
    else         { y0 = y[4]; y1 = y[5]; y2 = y[6]; y3 = y[7]; }

    const int eoff = l0 + nh * 4;   // == 4*t, coalesced
    const float* zp = z + (size_t)bd * kL + eoff;
    const float* ue = u + (size_t)bd * kL + eoff;
    float*       op = out + (size_t)bd * kL + eoff;

    float4 zv = *(const float4*)zp;
    float4 uv = *(const float4*)ue;
    float4 o;
    o.x = (y0 + uv.x * D_d) * zv.x / (1.f + __expf(-zv.x));
    o.y = (y1 + uv.y * D_d) * zv.y / (1.f + __expf(-zv.y));
    o.z = (y2 + uv.z * D_d) * zv.z / (1.f + __expf(-zv.z));
    o.w = (y3 + uv.w * D_d) * zv.w / (1.f + __expf(-zv.w));
    *(float4*)op = o;
}

}  // namespace

extern "C" void kernel_launch(void* const* d_in, const int* in_sizes, int n_in,
                              void* d_out, int out_size, void* d_ws, size_t ws_size,
                              hipStream_t stream) {
    const float* u     = (const float*)d_in[0];
    const float* delta = (const float*)d_in[1];
    const float* A     = (const float*)d_in[2];
    const float* Bm    = (const float*)d_in[3];
    const float* Cm    = (const float*)d_in[4];
    const float* Dv    = (const float*)d_in[5];
    const float* z     = (const float*)d_in[6];
    float* out = (float*)d_out;

    dim3 grid(2 * kD);
    dim3 block(kT);
    hipLaunchKernelGGL(selscan, grid, block, 0, stream,
                       u, delta, A, Bm, Cm, Dv, z, out);
}